// Round 7
// baseline (318.348 us; speedup 1.0000x reference)
//
#include <hip/hip_runtime.h>
#include <hip/hip_fp16.h>

#define EPS 1e-5f
#define CPAD 16  // cnt padded to one int per 64B line

typedef unsigned short ushort_t;
typedef unsigned long long u64;

__device__ __forceinline__ int rfl(int v) { return __builtin_amdgcn_readfirstlane(v); }

// ---- shared helpers: W staged in LDS as float2{W[k][m], W[k][m+32]} ---------

__device__ __forceinline__ void stage_W(const float* __restrict__ W, float2* Wp) {
    for (int j = threadIdx.x; j < 2048; j += 256) {
        int k = j >> 5, m = j & 31;
        Wp[j] = make_float2(W[k * 64 + m], W[k * 64 + m + 32]);
    }
}

// y (64 feats) -> t = y @ W.  All 64 lanes hold identical (yx,yy) for m=lane&31.
// Halves split the k-range; ONE shfl per k serves both (lane 32+mp holds yy_mp).
__device__ __forceinline__ float2 transform64(float yx, float yy, int sub, int m,
                                              const float2* Wp) {
    float bc = sub ? yy : yx;
    float tx = 0.f, ty = 0.f;
#pragma unroll
    for (int mp = 0; mp < 32; ++mp) {
        int k = (sub << 5) | mp;
        float yk = __shfl(bc, k);
        float2 w = Wp[(k << 5) | m];
        tx = fmaf(yk, w.x, tx);
        ty = fmaf(yk, w.y, ty);
    }
    tx += __shfl_xor(tx, 32);
    ty += __shfl_xor(ty, 32);
    return make_float2(tx, ty);
}

// ============== K1: edge histogram+rank  ||  input MLP (h only) ==============

__global__ void k_hist_mlp(const int* __restrict__ col, int* __restrict__ cnt,
                           ushort_t* __restrict__ rank, int e, int histBlocks,
                           const float* __restrict__ x, const float* __restrict__ Win,
                           const float* __restrict__ bin, float2* __restrict__ h2, int n) {
    if (blockIdx.x < histBlocks) {
        int i = blockIdx.x * 256 + threadIdx.x;
        if (i < e) {
            int old = atomicAdd(&cnt[(size_t)col[i] * CPAD], 1);
            rank[i] = (ushort_t)old;
        }
        return;
    }
    int b = blockIdx.x - histBlocks;
    int wv = threadIdx.x >> 6, lane = threadIdx.x & 63;
    int node = b * 4 + wv;
    if (node >= n) return;
    int m = lane & 31;
    float ax = bin[m], ay = bin[m + 32];
    const float* xr = x + (size_t)node * 16;
#pragma unroll
    for (int k = 0; k < 16; ++k) {
        float xv = xr[k];
        ax += xv * Win[k * 64 + m];
        ay += xv * Win[k * 64 + m + 32];
    }
    ax = fmaxf(ax, 0.0f);
    ay = fmaxf(ay, 0.0f);
    if (lane < 32) h2[(size_t)node * 32 + m] = make_float2(ax, ay);
}

// ============== scan phase A: per-256-chunk sums =============================

__global__ void k_scanA(const int* __restrict__ cnt, int* __restrict__ bsum, int n) {
    __shared__ int ws[4];
    int t = threadIdx.x, lane = t & 63, wv = t >> 6;
    int i = blockIdx.x * 256 + t;
    int v = (i < n) ? cnt[(size_t)i * CPAD] : 0;
    int x = v;
#pragma unroll
    for (int off = 32; off; off >>= 1) x += __shfl_xor(x, off);
    if (lane == 0) ws[wv] = x;
    __syncthreads();
    if (t == 0) bsum[blockIdx.x] = ws[0] + ws[1] + ws[2] + ws[3];
}

// ============== scan phase B: fused top-scan + apply (+dinv) =================

__global__ void k_scanB(const int* __restrict__ cnt, const int* __restrict__ bsum,
                        int* __restrict__ start, float* __restrict__ dinv, int n) {
    __shared__ int ws[4], ws2[4];
    __shared__ int bofs_s;
    int t = threadIdx.x, lane = t & 63, wv = t >> 6;
    // block offset = sum of bsum[j], j < blockIdx.x  (nb <= 256 assumed: N<=65536)
    int p = 0;
    for (int j = t; j < (int)blockIdx.x; j += 256) p += bsum[j];
    int pr = p;
#pragma unroll
    for (int off = 32; off; off >>= 1) pr += __shfl_xor(pr, off);
    if (lane == 0) ws[wv] = pr;
    __syncthreads();
    if (t == 0) bofs_s = ws[0] + ws[1] + ws[2] + ws[3];
    __syncthreads();
    int bofs = bofs_s;
    int i = blockIdx.x * 256 + t;
    int v = (i < n) ? cnt[(size_t)i * CPAD] : 0;
    int x = v;
#pragma unroll
    for (int off = 1; off < 64; off <<= 1) {
        int y = __shfl_up(x, off);
        if (lane >= off) x += y;
    }
    if (lane == 63) ws2[wv] = x;
    __syncthreads();
    int wofs = 0;
#pragma unroll
    for (int w = 0; w < 4; ++w) wofs += (w < wv) ? ws2[w] : 0;
    if (i < n) {
        start[i] = bofs + wofs + (x - v);
        dinv[i] = rsqrtf((float)(v + 1));
        if (i == n - 1) start[n] = bofs + wofs + x;  // grand total
    }
}

// ============== K2: bucket scatter  ||  layer-0 transform ====================

__global__ void k_bucket_transform(const int* __restrict__ row, const int* __restrict__ col,
                                   const int* __restrict__ start, const ushort_t* __restrict__ rank,
                                   ushort_t* __restrict__ bRow, int e, int ebBlocks,
                                   const float2* __restrict__ h2, const float* __restrict__ Wc,
                                   const float* __restrict__ dinv, __half2* __restrict__ ts, int n) {
    if (blockIdx.x < ebBlocks) {
        int i = blockIdx.x * 256 + threadIdx.x;
        if (i < e) bRow[start[col[i]] + (int)rank[i]] = (ushort_t)row[i];
        return;
    }
    __shared__ float2 Wp[2048];
    stage_W(Wc, Wp);
    __syncthreads();
    int b = blockIdx.x - ebBlocks;
    int wv = threadIdx.x >> 6, lane = threadIdx.x & 63;
    int node = b * 4 + wv;
    if (node >= n) return;
    int sub = lane >> 5, m = lane & 31;
    float2 hv = h2[(size_t)node * 32 + m];  // both halves read same -> identical
    float2 tr = transform64(hv.x, hv.y, sub, m, Wp);
    float dv = dinv[node];
    if (!sub) ts[(size_t)node * 32 + m] = __floats2half2_rn(tr.x * dv, tr.y * dv);
}

// ====== gather + LN + relu + residual + fused next-transform / output head ===
// Scalar u64 loads of 4-edge bRow packs (uniform addr); 2 edges per ts load.

__global__ void k_gather(const int* __restrict__ start, const ushort_t* __restrict__ bRow,
                         const __half2* __restrict__ ts, const float* __restrict__ dinv,
                         const float* __restrict__ bc, const float* __restrict__ gm,
                         const float* __restrict__ bt, float2* __restrict__ h2, int n,
                         const float* __restrict__ WcN, __half2* __restrict__ tsOut, int do_next,
                         const float* __restrict__ Wout, const float* __restrict__ bout,
                         float* __restrict__ out, int do_out) {
    __shared__ float2 Wp[2048];
    if (do_next) stage_W(WcN, Wp);   // do_next is uniform (kernel arg)
    __syncthreads();
    int wv = threadIdx.x >> 6, lane = threadIdx.x & 63;
    int node = blockIdx.x * 4 + wv;
    if (node >= n) return;
    int sub = lane >> 5, m = lane & 31;
    int e0 = rfl(start[node]);
    int e1 = rfl(start[node + 1]);

    float a0x = 0.f, a0y = 0.f, a1x = 0.f, a1y = 0.f;

    int bs = (e0 + 3) & ~3;   // aligned body start
    int be = e1 & ~3;         // aligned body end
    if (be <= bs) { bs = e1; be = e1; }  // no body: head covers [e0,e1)

    // head: per-edge (uniform broadcast load), accumulate only in sub==0 half
    for (int i = e0; i < bs; ++i) {
        int r = (int)bRow[i];
        __half2 v = ts[((size_t)r << 5) + m];
        if (!sub) { a0x += __low2float(v); a0y += __high2float(v); }
    }
    // body: 4 edges per scalar u64; lanes sub=0 take edges {0,2}, sub=1 {1,3}
    for (int e = bs; e < be; e += 4) {
        u64 pk = *(const u64*)(bRow + e);  // uniform addr -> scalar load
        int r0 = (int)(pk & 0xFFFF);
        int r1 = (int)((pk >> 16) & 0xFFFF);
        int r2 = (int)((pk >> 32) & 0xFFFF);
        int r3 = (int)(pk >> 48);
        int rA = sub ? r1 : r0;
        int rB = sub ? r3 : r2;
        __half2 vA = ts[((size_t)rA << 5) + m];
        __half2 vB = ts[((size_t)rB << 5) + m];
        a0x += __low2float(vA); a0y += __high2float(vA);
        a1x += __low2float(vB); a1y += __high2float(vB);
    }
    // tail
    for (int i = be; i < e1; ++i) {
        int r = (int)bRow[i];
        __half2 v = ts[((size_t)r << 5) + m];
        if (!sub) { a0x += __low2float(v); a0y += __high2float(v); }
    }

    float accx = a0x + a1x, accy = a0y + a1y;
    accx += __shfl_xor(accx, 32);   // combine halves -> identical in both
    accy += __shfl_xor(accy, 32);

    size_t idx = (size_t)node * 32 + m;
    __half2 self = ts[idx];
    float dv = dinv[node];
    float vx = (accx + __low2float(self)) * dv + bc[m];
    float vy = (accy + __high2float(self)) * dv + bc[m + 32];
    // layernorm over 64 feats (2/lane; reduce within 32-lane half, halves equal)
    float s = vx + vy;
#pragma unroll
    for (int off = 16; off; off >>= 1) s += __shfl_xor(s, off);
    float mu = s * (1.0f / 64.0f);
    float dx = vx - mu, dy = vy - mu;
    float q = dx * dx + dy * dy;
#pragma unroll
    for (int off = 16; off; off >>= 1) q += __shfl_xor(q, off);
    float inv = rsqrtf(q * (1.0f / 64.0f) + EPS);
    float2 hv = h2[idx];
    float yx = fmaxf(dx * inv * gm[m] + bt[m], 0.0f) + hv.x;
    float yy = fmaxf(dy * inv * gm[m + 32] + bt[m + 32], 0.0f) + hv.y;
    if (!sub) h2[idx] = make_float2(yx, yy);
    if (do_next) {
        float2 tr = transform64(yx, yy, sub, m, Wp);
        if (!sub) tsOut[idx] = __floats2half2_rn(tr.x * dv, tr.y * dv);
    }
    if (do_out) {
        float o = yx * Wout[m] + yy * Wout[m + 32];
#pragma unroll
        for (int off = 16; off; off >>= 1) o += __shfl_xor(o, off);
        if (lane == 0) out[node] = o + bout[0];
    }
}

extern "C" void kernel_launch(void* const* d_in, const int* in_sizes, int n_in,
                              void* d_out, int out_size, void* d_ws, size_t ws_size,
                              hipStream_t stream) {
    const float* x     = (const float*)d_in[0];
    const int*   eidx  = (const int*)d_in[1];
    const float* Win   = (const float*)d_in[2];
    const float* bin   = (const float*)d_in[3];
    const float* Wconv = (const float*)d_in[4];
    const float* bconv = (const float*)d_in[5];
    const float* gamma = (const float*)d_in[6];
    const float* beta  = (const float*)d_in[7];
    const float* Wout  = (const float*)d_in[8];
    const float* bout  = (const float*)d_in[9];
    float* out = (float*)d_out;

    const int N = in_sizes[0] / 16;
    const int E = in_sizes[1] / 2;
    const int L = in_sizes[4] / (64 * 64);

    const int* row = eidx;
    const int* col = eidx + E;

    char* ws = (char*)d_ws;
    size_t off = 0;
    auto alloc = [&](size_t bytes) -> void* {
        size_t p = off;
        off += (bytes + 255) & ~(size_t)255;
        return (void*)(ws + p);
    };
    int*      cnt    = (int*)alloc((size_t)N * CPAD * 4);
    ushort_t* rank   = (ushort_t*)alloc((size_t)E * 2);
    int*      bsum   = (int*)alloc(1024 * 4);
    int*      startA = (int*)alloc((size_t)(N + 1) * 4);
    float*    dinv   = (float*)alloc((size_t)N * 4);
    ushort_t* bRow   = (ushort_t*)alloc((size_t)E * 2 + 8);  // +8: u64 overread pad
    float2*   h2     = (float2*)alloc((size_t)N * 32 * 8);
    __half2*  tsA    = (__half2*)alloc((size_t)N * 32 * 4);
    __half2*  tsB    = (__half2*)alloc((size_t)N * 32 * 4);
    (void)ws_size;

    const int BT = 256;
    int gE1  = (E + BT - 1) / BT;      // 3125
    int gN64 = (N + 3) / 4;            // 12500
    int nb   = (N + 255) / 256;        // 196 (<=256 required by k_scanB)

    hipMemsetAsync(cnt, 0, (size_t)N * CPAD * 4, stream);
    k_hist_mlp<<<gE1 + gN64, BT, 0, stream>>>(col, cnt, rank, E, gE1,
                                              x, Win, bin, h2, N);
    k_scanA<<<nb, BT, 0, stream>>>(cnt, bsum, N);
    k_scanB<<<nb, BT, 0, stream>>>(cnt, bsum, startA, dinv, N);
    k_bucket_transform<<<gE1 + gN64, BT, 0, stream>>>(row, col, startA, rank, bRow, E, gE1,
                                                      h2, Wconv, dinv, tsA, N);

    __half2* bufs[2] = {tsA, tsB};
    for (int l = 0; l < L; ++l) {
        const float* bc = bconv + (size_t)l * 64;
        const float* gm = gamma + (size_t)l * 64;
        const float* bt = beta + (size_t)l * 64;
        int last = (l == L - 1);
        const float* WcN = last ? Wconv : Wconv + (size_t)(l + 1) * 64 * 64;
        k_gather<<<gN64, BT, 0, stream>>>(startA, bRow, bufs[l & 1], dinv, bc, gm, bt, h2, N,
                                          WcN, bufs[(l + 1) & 1], !last,
                                          Wout, bout, out, last);
    }
}

// Round 8
// 291.883 us; speedup vs baseline: 1.0907x; 1.0907x over previous
//
#include <hip/hip_runtime.h>
#include <hip/hip_fp16.h>

#define EPS 1e-5f
#define CPAD 16  // cnt padded to one int per 64B line

typedef unsigned short ushort_t;

// ---- shared helpers: W staged in LDS as float2{W[k][m], W[k][m+32]} ---------

__device__ __forceinline__ void stage_W(const float* __restrict__ W, float2* Wp) {
    for (int j = threadIdx.x; j < 2048; j += 256) {
        int k = j >> 5, m = j & 31;
        Wp[j] = make_float2(W[k * 64 + m], W[k * 64 + m + 32]);
    }
}

// y (64 feats) -> t = y @ W.  All 64 lanes hold identical (yx,yy) for m=lane&31.
// Halves split the k-range; ONE shfl per k serves both.
__device__ __forceinline__ float2 transform64(float yx, float yy, int sub, int m,
                                              const float2* Wp) {
    float bc = sub ? yy : yx;
    float tx = 0.f, ty = 0.f;
#pragma unroll
    for (int mp = 0; mp < 32; ++mp) {
        int k = (sub << 5) | mp;
        float yk = __shfl(bc, k);
        float2 w = Wp[(k << 5) | m];
        tx = fmaf(yk, w.x, tx);
        ty = fmaf(yk, w.y, ty);
    }
    tx += __shfl_xor(tx, 32);
    ty += __shfl_xor(ty, 32);
    return make_float2(tx, ty);
}

// ============== K1: edge histogram+rank  ||  input MLP (h only) ==============

__global__ void k_hist_mlp(const int* __restrict__ col, int* __restrict__ cnt,
                           ushort_t* __restrict__ rank, int e, int histBlocks,
                           const float* __restrict__ x, const float* __restrict__ Win,
                           const float* __restrict__ bin, float2* __restrict__ h2, int n) {
    if (blockIdx.x < histBlocks) {
        int i = blockIdx.x * 256 + threadIdx.x;
        if (i < e) {
            int old = atomicAdd(&cnt[(size_t)col[i] * CPAD], 1);
            rank[i] = (ushort_t)old;
        }
        return;
    }
    int b = blockIdx.x - histBlocks;
    int wv = threadIdx.x >> 6, lane = threadIdx.x & 63;
    int node = b * 4 + wv;
    if (node >= n) return;
    int m = lane & 31;
    float ax = bin[m], ay = bin[m + 32];
    const float* xr = x + (size_t)node * 16;
#pragma unroll
    for (int k = 0; k < 16; ++k) {
        float xv = xr[k];
        ax += xv * Win[k * 64 + m];
        ay += xv * Win[k * 64 + m + 32];
    }
    ax = fmaxf(ax, 0.0f);
    ay = fmaxf(ay, 0.0f);
    if (lane < 32) h2[(size_t)node * 32 + m] = make_float2(ax, ay);
}

// ============== scan phase A: per-256-chunk sums =============================

__global__ void k_scanA(const int* __restrict__ cnt, int* __restrict__ bsum, int n) {
    __shared__ int ws[4];
    int t = threadIdx.x, lane = t & 63, wv = t >> 6;
    int i = blockIdx.x * 256 + t;
    int v = (i < n) ? cnt[(size_t)i * CPAD] : 0;
    int x = v;
#pragma unroll
    for (int off = 32; off; off >>= 1) x += __shfl_xor(x, off);
    if (lane == 0) ws[wv] = x;
    __syncthreads();
    if (t == 0) bsum[blockIdx.x] = ws[0] + ws[1] + ws[2] + ws[3];
}

// ============== scan phase B: fused top-scan + apply (+dinv) =================

__global__ void k_scanB(const int* __restrict__ cnt, const int* __restrict__ bsum,
                        int* __restrict__ start, float* __restrict__ dinv, int n) {
    __shared__ int ws[4], ws2[4];
    __shared__ int bofs_s;
    int t = threadIdx.x, lane = t & 63, wv = t >> 6;
    int p = 0;
    for (int j = t; j < (int)blockIdx.x; j += 256) p += bsum[j];
    int pr = p;
#pragma unroll
    for (int off = 32; off; off >>= 1) pr += __shfl_xor(pr, off);
    if (lane == 0) ws[wv] = pr;
    __syncthreads();
    if (t == 0) bofs_s = ws[0] + ws[1] + ws[2] + ws[3];
    __syncthreads();
    int bofs = bofs_s;
    int i = blockIdx.x * 256 + t;
    int v = (i < n) ? cnt[(size_t)i * CPAD] : 0;
    int x = v;
#pragma unroll
    for (int off = 1; off < 64; off <<= 1) {
        int y = __shfl_up(x, off);
        if (lane >= off) x += y;
    }
    if (lane == 63) ws2[wv] = x;
    __syncthreads();
    int wofs = 0;
#pragma unroll
    for (int w = 0; w < 4; ++w) wofs += (w < wv) ? ws2[w] : 0;
    if (i < n) {
        start[i] = bofs + wofs + (x - v);
        dinv[i] = rsqrtf((float)(v + 1));
        if (i == n - 1) start[n] = bofs + wofs + x;  // grand total
    }
}

// ============== K2: bucket scatter  ||  layer-0 transform ====================

__global__ void k_bucket_transform(const int* __restrict__ row, const int* __restrict__ col,
                                   const int* __restrict__ start, const ushort_t* __restrict__ rank,
                                   ushort_t* __restrict__ bRow, int e, int ebBlocks,
                                   const float2* __restrict__ h2, const float* __restrict__ Wc,
                                   const float* __restrict__ dinv, __half2* __restrict__ ts, int n) {
    if (blockIdx.x < ebBlocks) {
        int i = blockIdx.x * 256 + threadIdx.x;
        if (i < e) bRow[start[col[i]] + (int)rank[i]] = (ushort_t)row[i];
        return;
    }
    __shared__ float2 Wp[2048];
    stage_W(Wc, Wp);
    __syncthreads();
    int b = blockIdx.x - ebBlocks;
    int wv = threadIdx.x >> 6, lane = threadIdx.x & 63;
    int node = b * 4 + wv;
    if (node >= n) return;
    int sub = lane >> 5, m = lane & 31;
    float2 hv = h2[(size_t)node * 32 + m];
    float2 tr = transform64(hv.x, hv.y, sub, m, Wp);
    float dv = dinv[node];
    if (!sub) ts[(size_t)node * 32 + m] = __floats2half2_rn(tr.x * dv, tr.y * dv);
}

// ====== gather + LN + relu + residual + fused next-transform / output head ===
// R5-style chunk+shfl body, 16 edge-slots (8 independent loads) in flight.

__global__ void k_gather(const int* __restrict__ start, const ushort_t* __restrict__ bRow,
                         const __half2* __restrict__ ts, const float* __restrict__ dinv,
                         const float* __restrict__ bc, const float* __restrict__ gm,
                         const float* __restrict__ bt, float2* __restrict__ h2, int n,
                         const float* __restrict__ WcN, __half2* __restrict__ tsOut, int do_next,
                         const float* __restrict__ Wout, const float* __restrict__ bout,
                         float* __restrict__ out, int do_out) {
    __shared__ float2 Wp[2048];
    if (do_next) stage_W(WcN, Wp);   // do_next is uniform (kernel arg)
    __syncthreads();
    int wv = threadIdx.x >> 6, lane = threadIdx.x & 63;
    int node = blockIdx.x * 4 + wv;
    if (node >= n) return;
    int sub = lane >> 5, m = lane & 31;
    int e0 = start[node], e1 = start[node + 1];

    // hoist independent epilogue loads so they overlap the gather
    size_t idx = (size_t)node * 32 + m;
    __half2 self = ts[idx];
    float2 hv = h2[idx];
    float dv = dinv[node];

    float ax0 = 0.f, ay0 = 0.f, ax1 = 0.f, ay1 = 0.f;
    float ax2 = 0.f, ay2 = 0.f, ax3 = 0.f, ay3 = 0.f;
    float ax4 = 0.f, ay4 = 0.f, ax5 = 0.f, ay5 = 0.f;
    float ax6 = 0.f, ay6 = 0.f, ax7 = 0.f, ay7 = 0.f;

    for (int base = e0; base < e1; base += 64) {
        int cnt = min(64, e1 - base);
        int rE = (int)bRow[base + ((lane < cnt) ? lane : 0)];
        for (int j = 0; j < 64; j += 16) {
            if (j >= cnt) break;  // wave-uniform
            // 16 edge slots; sub=0 lanes take even slots, sub=1 odd -> 8 loads
            int j0 = j + 0 + sub, j1 = j + 2 + sub, j2 = j + 4 + sub, j3 = j + 6 + sub;
            int j4 = j + 8 + sub, j5 = j + 10 + sub, j6 = j + 12 + sub, j7 = j + 14 + sub;
            int ok0 = j0 < cnt, ok1 = j1 < cnt, ok2 = j2 < cnt, ok3 = j3 < cnt;
            int ok4 = j4 < cnt, ok5 = j5 < cnt, ok6 = j6 < cnt, ok7 = j7 < cnt;
            int r0 = __shfl(rE, ok0 ? j0 : 0);
            int r1 = __shfl(rE, ok1 ? j1 : 0);
            int r2 = __shfl(rE, ok2 ? j2 : 0);
            int r3 = __shfl(rE, ok3 ? j3 : 0);
            int r4 = __shfl(rE, ok4 ? j4 : 0);
            int r5 = __shfl(rE, ok5 ? j5 : 0);
            int r6 = __shfl(rE, ok6 ? j6 : 0);
            int r7 = __shfl(rE, ok7 ? j7 : 0);
            __half2 v0 = ts[((size_t)r0 << 5) + m];
            __half2 v1 = ts[((size_t)r1 << 5) + m];
            __half2 v2 = ts[((size_t)r2 << 5) + m];
            __half2 v3 = ts[((size_t)r3 << 5) + m];
            __half2 v4 = ts[((size_t)r4 << 5) + m];
            __half2 v5 = ts[((size_t)r5 << 5) + m];
            __half2 v6 = ts[((size_t)r6 << 5) + m];
            __half2 v7 = ts[((size_t)r7 << 5) + m];
            if (ok0) { ax0 += __low2float(v0); ay0 += __high2float(v0); }
            if (ok1) { ax1 += __low2float(v1); ay1 += __high2float(v1); }
            if (ok2) { ax2 += __low2float(v2); ay2 += __high2float(v2); }
            if (ok3) { ax3 += __low2float(v3); ay3 += __high2float(v3); }
            if (ok4) { ax4 += __low2float(v4); ay4 += __high2float(v4); }
            if (ok5) { ax5 += __low2float(v5); ay5 += __high2float(v5); }
            if (ok6) { ax6 += __low2float(v6); ay6 += __high2float(v6); }
            if (ok7) { ax7 += __low2float(v7); ay7 += __high2float(v7); }
        }
    }
    float accx = ((ax0 + ax1) + (ax2 + ax3)) + ((ax4 + ax5) + (ax6 + ax7));
    float accy = ((ay0 + ay1) + (ay2 + ay3)) + ((ay4 + ay5) + (ay6 + ay7));
    accx += __shfl_xor(accx, 32);   // combine halves -> identical in both
    accy += __shfl_xor(accy, 32);

    float vx = (accx + __low2float(self)) * dv + bc[m];
    float vy = (accy + __high2float(self)) * dv + bc[m + 32];
    // layernorm over 64 feats (2/lane; reduce within 32-lane half, halves equal)
    float s = vx + vy;
#pragma unroll
    for (int off = 16; off; off >>= 1) s += __shfl_xor(s, off);
    float mu = s * (1.0f / 64.0f);
    float dx = vx - mu, dy = vy - mu;
    float q = dx * dx + dy * dy;
#pragma unroll
    for (int off = 16; off; off >>= 1) q += __shfl_xor(q, off);
    float inv = rsqrtf(q * (1.0f / 64.0f) + EPS);
    float yx = fmaxf(dx * inv * gm[m] + bt[m], 0.0f) + hv.x;
    float yy = fmaxf(dy * inv * gm[m + 32] + bt[m + 32], 0.0f) + hv.y;
    if (!sub) h2[idx] = make_float2(yx, yy);
    if (do_next) {
        float2 tr = transform64(yx, yy, sub, m, Wp);
        if (!sub) tsOut[idx] = __floats2half2_rn(tr.x * dv, tr.y * dv);
    }
    if (do_out) {
        float o = yx * Wout[m] + yy * Wout[m + 32];
#pragma unroll
        for (int off = 16; off; off >>= 1) o += __shfl_xor(o, off);
        if (lane == 0) out[node] = o + bout[0];
    }
}

extern "C" void kernel_launch(void* const* d_in, const int* in_sizes, int n_in,
                              void* d_out, int out_size, void* d_ws, size_t ws_size,
                              hipStream_t stream) {
    const float* x     = (const float*)d_in[0];
    const int*   eidx  = (const int*)d_in[1];
    const float* Win   = (const float*)d_in[2];
    const float* bin   = (const float*)d_in[3];
    const float* Wconv = (const float*)d_in[4];
    const float* bconv = (const float*)d_in[5];
    const float* gamma = (const float*)d_in[6];
    const float* beta  = (const float*)d_in[7];
    const float* Wout  = (const float*)d_in[8];
    const float* bout  = (const float*)d_in[9];
    float* out = (float*)d_out;

    const int N = in_sizes[0] / 16;
    const int E = in_sizes[1] / 2;
    const int L = in_sizes[4] / (64 * 64);

    const int* row = eidx;
    const int* col = eidx + E;

    char* ws = (char*)d_ws;
    size_t off = 0;
    auto alloc = [&](size_t bytes) -> void* {
        size_t p = off;
        off += (bytes + 255) & ~(size_t)255;
        return (void*)(ws + p);
    };
    int*      cnt    = (int*)alloc((size_t)N * CPAD * 4);
    ushort_t* rank   = (ushort_t*)alloc((size_t)E * 2);
    int*      bsum   = (int*)alloc(1024 * 4);
    int*      startA = (int*)alloc((size_t)(N + 1) * 4);
    float*    dinv   = (float*)alloc((size_t)N * 4);
    ushort_t* bRow   = (ushort_t*)alloc((size_t)E * 2 + 8);
    float2*   h2     = (float2*)alloc((size_t)N * 32 * 8);
    __half2*  tsA    = (__half2*)alloc((size_t)N * 32 * 4);
    __half2*  tsB    = (__half2*)alloc((size_t)N * 32 * 4);
    (void)ws_size;

    const int BT = 256;
    int gE1  = (E + BT - 1) / BT;      // 3125
    int gN64 = (N + 3) / 4;            // 12500
    int nb   = (N + 255) / 256;        // 196 (<=256 required by k_scanB)

    hipMemsetAsync(cnt, 0, (size_t)N * CPAD * 4, stream);
    k_hist_mlp<<<gE1 + gN64, BT, 0, stream>>>(col, cnt, rank, E, gE1,
                                              x, Win, bin, h2, N);
    k_scanA<<<nb, BT, 0, stream>>>(cnt, bsum, N);
    k_scanB<<<nb, BT, 0, stream>>>(cnt, bsum, startA, dinv, N);
    k_bucket_transform<<<gE1 + gN64, BT, 0, stream>>>(row, col, startA, rank, bRow, E, gE1,
                                                      h2, Wconv, dinv, tsA, N);

    __half2* bufs[2] = {tsA, tsB};
    for (int l = 0; l < L; ++l) {
        const float* bc = bconv + (size_t)l * 64;
        const float* gm = gamma + (size_t)l * 64;
        const float* bt = beta + (size_t)l * 64;
        int last = (l == L - 1);
        const float* WcN = last ? Wconv : Wconv + (size_t)(l + 1) * 64 * 64;
        k_gather<<<gN64, BT, 0, stream>>>(startA, bRow, bufs[l & 1], dinv, bc, gm, bt, h2, N,
                                          WcN, bufs[(l + 1) & 1], !last,
                                          Wout, bout, out, last);
    }
}